// Round 6
// baseline (296.397 us; speedup 1.0000x reference)
//
#include <hip/hip_runtime.h>

// B=8, N=2048, C=512. Flash attention + fp16 MFMA pipeline.
// attn r6: r5 + G reg-staged (issue-early/write-late) into padded [512][40]
// LDS layout -> kills the 8-way PV bank conflicts. K via global_load_lds with
// XOR swizzle (unchanged). QK(t+1) || softmax(t) || PV(t), 1 barrier/tile.
// ws layout: xb(16MB) h(16MB) l(16MB) gT(16MB) y(16MB) Wt(2MB)  [fp16 bits]

typedef __attribute__((ext_vector_type(4))) float f32x4;
typedef __attribute__((ext_vector_type(8))) short s16x8;      // fp16 bit-patterns
typedef __attribute__((ext_vector_type(4))) short s16x4;
typedef __attribute__((ext_vector_type(8))) _Float16 f16x8;   // MFMA operand
typedef __attribute__((ext_vector_type(4))) unsigned u32x4;

typedef unsigned int u32;
typedef __attribute__((address_space(1))) const u32 gu32;
typedef __attribute__((address_space(3))) u32 lu32;

__device__ __forceinline__ void gload16(const short* g, short* l) {
  __builtin_amdgcn_global_load_lds((gu32*)g, (lu32*)l, 16, 0, 0);
}

__device__ __forceinline__ short f2h(float f) {
  _Float16 h = (_Float16)f;
  return __builtin_bit_cast(short, h);
}

__device__ __forceinline__ unsigned pk2h(float a, float b) {
  return __builtin_bit_cast(unsigned, __builtin_amdgcn_cvt_pkrtz(a, b));
}

#define MFMA(a, b, c) __builtin_amdgcn_mfma_f32_16x16x32_f16(a, b, c, 0, 0, 0)

// ---------------- conversion kernels ----------------

__global__ __launch_bounds__(256) void conv_x_kernel(const float* __restrict__ x,
                                                     short* __restrict__ xb) {
  int i = blockIdx.x * 256 + threadIdx.x;
  const float4* xv = (const float4*)x;
  float4 a = xv[2 * i], b = xv[2 * i + 1];
  s16x8 o;
  o[0] = f2h(a.x); o[1] = f2h(a.y); o[2] = f2h(a.z); o[3] = f2h(a.w);
  o[4] = f2h(b.x); o[5] = f2h(b.y); o[6] = f2h(b.z); o[7] = f2h(b.w);
  ((s16x8*)xb)[i] = o;
}

__global__ __launch_bounds__(256) void conv_w_kernel(const float* __restrict__ Wh,
                                                     const float* __restrict__ Wl,
                                                     const float* __restrict__ Wg,
                                                     const float* __restrict__ Wm,
                                                     short* __restrict__ Wt) {
  int idx = blockIdx.x * 256 + threadIdx.x;
  int k = idx & 511, n = (idx >> 9) & 511, w = idx >> 18;
  const float* W = (w == 0) ? Wh : (w == 1) ? Wl : (w == 2) ? Wg : Wm;
  Wt[idx] = f2h(W[k * 512 + n]);
}

// ---------------- fused 3-way MLP GEMM ----------------

__global__ __launch_bounds__(256) void mlp3_kernel(const short* __restrict__ A,
                                                   const short* __restrict__ Wt_all,
                                                   const float* __restrict__ bh,
                                                   const float* __restrict__ bl,
                                                   const float* __restrict__ bg,
                                                   short* __restrict__ h,
                                                   short* __restrict__ l,
                                                   short* __restrict__ gT) {
  int z = blockIdx.z;
  const short* Wt = Wt_all + z * 262144;
  const float* bias = (z == 0) ? bh : (z == 1) ? bl : bg;

  __shared__ __align__(16) short lds_a[128 * 40];
  __shared__ __align__(16) short lds_b[128 * 40];
  int tid = threadIdx.x, lane = tid & 63, w = tid >> 6;
  int wm = w >> 1, wn = w & 1;
  int bm = blockIdx.x * 128, bn = blockIdx.y * 128;

  f32x4 acc[4][4];
#pragma unroll
  for (int mi = 0; mi < 4; ++mi)
#pragma unroll
    for (int ni = 0; ni < 4; ++ni) acc[mi][ni] = (f32x4){0.f, 0.f, 0.f, 0.f};

  for (int k0 = 0; k0 < 512; k0 += 32) {
#pragma unroll
    for (int it = 0; it < 2; ++it) {
      int chunk = tid + it * 256;
      int row = chunk >> 2, c8 = (chunk & 3) * 8;
      *(s16x8*)&lds_a[row * 40 + c8] =
          *(const s16x8*)&A[(size_t)(bm + row) * 512 + k0 + c8];
      *(s16x8*)&lds_b[row * 40 + c8] =
          *(const s16x8*)&Wt[(bn + row) * 512 + k0 + c8];
    }
    __syncthreads();
    f16x8 af[4], bfr[4];
#pragma unroll
    for (int mi = 0; mi < 4; ++mi)
      af[mi] = *(const f16x8*)&lds_a[(wm * 64 + mi * 16 + (lane & 15)) * 40 +
                                     (lane >> 4) * 8];
#pragma unroll
    for (int ni = 0; ni < 4; ++ni)
      bfr[ni] = *(const f16x8*)&lds_b[(wn * 64 + ni * 16 + (lane & 15)) * 40 +
                                      (lane >> 4) * 8];
#pragma unroll
    for (int mi = 0; mi < 4; ++mi)
#pragma unroll
      for (int ni = 0; ni < 4; ++ni) acc[mi][ni] = MFMA(af[mi], bfr[ni], acc[mi][ni]);
    __syncthreads();
  }

#pragma unroll
  for (int mi = 0; mi < 4; ++mi)
#pragma unroll
    for (int ni = 0; ni < 4; ++ni) {
      int col = bn + wn * 64 + ni * 16 + (lane & 15);
      float bv = bias[col];
#pragma unroll
      for (int r = 0; r < 4; ++r) {
        int row = bm + wm * 64 + mi * 16 + (lane >> 4) * 4 + r;
        float v = fmaxf(acc[mi][ni][r] + bv, 0.0f);
        short o = f2h(v);
        if (z == 0) h[(size_t)row * 512 + col] = o;
        else if (z == 1) l[(size_t)row * 512 + col] = o;
        else {
          int bb = row >> 11, mm = row & 2047;
          gT[((size_t)bb * 512 + col) * 2048 + mm] = o;
        }
      }
    }
}

// ---------------- flash attention + residual ----------------
// 256 blocks x 256 threads (4 waves x 16 q, full D). KVBLK=32.
// S^T = mfma(K,Q): lane owns query (lane&15), keys (lane>>4)*4+r (+16).
// PV: O^T = mfma(G^T, P^T) with P^T built in-register via permlane swaps.
// G reg-staged into padded [512][40] (80B stride: bank-balanced b128 reads).

#define GSTR 40

__global__ __launch_bounds__(256, 1) void attn_kernel(const short* __restrict__ lmat,
                                                      const short* __restrict__ hmat,
                                                      const short* __restrict__ gT,
                                                      const float* __restrict__ x,
                                                      short* __restrict__ y) {
  __shared__ __align__(16) short kbuf[2][16384];       // [32 keys][512], XOR-swizzled
  __shared__ __align__(16) short gbuf[2][512 * GSTR];  // [512 c][32 keys] pad->40
  int tid = threadIdx.x, lane = tid & 63, w = tid >> 6;
  int swz = (blockIdx.x & 7) * 32 + (blockIdx.x >> 3);
  int b = swz >> 5, qt = swz & 31;
  int q0 = qt * 64 + w * 16;
  const short* lb = lmat + (size_t)b * 2048 * 512;
  const short* hb = hmat + (size_t)b * 2048 * 512;
  const short* gb = gT + (size_t)b * 512 * 2048;

  int r0 = lane & 15, g = lane >> 4;

  // Q fragments (B-operand: lane&15 = query col, k-chunk g*8): 64 VGPR
  f16x8 qf[16];
  {
    int q = q0 + r0;
#pragma unroll
    for (int ks = 0; ks < 16; ++ks)
      qf[ks] = *(const f16x8*)&lb[(size_t)q * 512 + ks * 32 + g * 8];
  }
  f32x4 accO[32];  // O^T: query r0, d = nf*16 + g*4 + r
#pragma unroll
  for (int i = 0; i < 32; ++i) accO[i] = (f32x4){0.f, 0.f, 0.f, 0.f};
  float mrun = -3e38f, lsumL = 0.f;  // per-lane (one query), partial over g

  // G staging registers: 8 x 16B. Loaded early (oldest vmem), written late.
  s16x8 greg[8];
  int gc = (w * 8) * 16 + (lane >> 2);     // first chunk's c-row for this thread
  int gk = (lane & 3) * 8;                 // key sub-chunk

  auto loadG = [&](int t) {
    int key0 = t * 32;
#pragma unroll
    for (int j = 0; j < 8; ++j)
      greg[j] = *(const s16x8*)&gb[(size_t)(gc + j * 16) * 2048 + key0 + gk];
  };
  auto writeG = [&](int buf) {
#pragma unroll
    for (int j = 0; j < 8; ++j)
      *(s16x8*)&gbuf[buf][(gc + j * 16) * GSTR + gk] = greg[j];
  };
  auto stageK = [&](int buf, int t) {
    int key0 = t * 32;
    short* kd = &kbuf[buf][0];
#pragma unroll
    for (int j = 0; j < 8; ++j) {
      int wl = w * 8 + j;
      gload16(hb + (size_t)(key0 + wl) * 512 + (((lane * 16) ^ ((wl & 7) << 4)) >> 1),
              kd + wl * 512);
    }
  };
  auto QK = [&](int buf, f32x4& o0, f32x4& o1) {
    const short* kb = &kbuf[buf][0];
#pragma unroll
    for (int ks = 0; ks < 16; ++ks) {
      f16x8 k0f = *(const f16x8*)&kb[(r0 * 512 + ks * 32 + g * 8) ^ ((r0 & 7) << 3)];
      o0 = MFMA(k0f, qf[ks], o0);
      f16x8 k1f = *(const f16x8*)&kb[((r0 + 16) * 512 + ks * 32 + g * 8) ^ ((r0 & 7) << 3)];
      o1 = MFMA(k1f, qf[ks], o1);
    }
  };

  // prologue: G(0) regs -> gbuf0; K(0),K(1) via DMA; QK(0)
  loadG(0);
  stageK(0, 0);
  stageK(1, 1);
  writeG(0);           // waits only G loads (oldest); K DMA stays in flight
  __syncthreads();     // drains all: K(0),K(1) landed, G(0) visible
  f32x4 sc0 = {0.f, 0.f, 0.f, 0.f}, sc1 = {0.f, 0.f, 0.f, 0.f};
  f32x4 sn0, sn1;
  QK(0, sc0, sc1);
  __syncthreads();     // all waves done reading kbuf0 before t=0 overwrites it

  for (int t = 0; t < 64; ++t) {
    // issue next G reg-loads FIRST (so writeG's wait leaves K DMA in flight),
    // then K DMA two ahead.
    if (t < 63) loadG(t + 1);
    if (t < 62) stageK(t & 1, t + 2);

    // QK(t+1) — independent of softmax(t); reads kbuf[(t+1)&1]
    sn0 = (f32x4){0.f, 0.f, 0.f, 0.f};
    sn1 = (f32x4){0.f, 0.f, 0.f, 0.f};
    if (t < 63) {
      __builtin_amdgcn_s_setprio(1);
      QK((t + 1) & 1, sn0, sn1);
      __builtin_amdgcn_s_setprio(0);
    }

    // ---- softmax(t): lane-local over 8 scores + 2 shuffles ----
    float m2 = fmaxf(fmaxf(fmaxf(sc0[0], sc0[1]), fmaxf(sc0[2], sc0[3])),
                     fmaxf(fmaxf(sc1[0], sc1[1]), fmaxf(sc1[2], sc1[3])));
    m2 = fmaxf(m2, __shfl_xor(m2, 16));
    m2 = fmaxf(m2, __shfl_xor(m2, 32));
    bool ok = (m2 <= mrun + 8.0f);  // defer-max THR=8
    if (!__all((int)ok)) {
      float mnew = fmaxf(mrun, m2);
      float s = __expf(mrun - mnew);
      mrun = mnew;
      lsumL *= s;
#pragma unroll
      for (int nf = 0; nf < 32; ++nf) accO[nf] *= s;
    }
    float a0 = __expf(sc0[0] - mrun), a1 = __expf(sc0[1] - mrun);
    float a2 = __expf(sc0[2] - mrun), a3 = __expf(sc0[3] - mrun);
    float b0 = __expf(sc1[0] - mrun), b1 = __expf(sc1[1] - mrun);
    float b2 = __expf(sc1[2] - mrun), b3 = __expf(sc1[3] - mrun);
    lsumL += (a0 + a1) + (a2 + a3) + (b0 + b1) + (b2 + b3);

    // ---- P^T fragment in-register (B-operand: lane r0 = q, k = g*8+j) ----
    unsigned A0 = pk2h(a0, a1), A1 = pk2h(a2, a3);
    unsigned B0 = pk2h(b0, b1), B1 = pk2h(b2, b3);
    asm volatile("v_permlane32_swap_b32 %0, %1" : "+v"(A0), "+v"(B0));
    asm volatile("v_permlane16_swap_b32 %0, %1" : "+v"(A0), "+v"(B0));
    asm volatile("v_permlane32_swap_b32 %0, %1" : "+v"(A1), "+v"(B1));
    asm volatile("v_permlane16_swap_b32 %0, %1" : "+v"(A1), "+v"(B1));
    u32x4 pw = {A0, A1, B0, B1};
    f16x8 pfrag = __builtin_bit_cast(f16x8, pw);

    // ---- PV(t): O^T += G^T-frag x P^T-frag (bank-balanced padded reads) ----
    const short* gp = &gbuf[t & 1][0];
    __builtin_amdgcn_s_setprio(1);
#pragma unroll
    for (int nf = 0; nf < 32; ++nf) {
      f16x8 gf = *(const f16x8*)&gp[(nf * 16 + r0) * GSTR + g * 8];
      accO[nf] = MFMA(gf, pfrag, accO[nf]);
    }
    __builtin_amdgcn_s_setprio(0);

    // write G(t+1) into the buffer PV(t+1) will read (safe: last read at t-1)
    if (t < 63) writeG((t + 1) & 1);

    __syncthreads();
    sc0 = sn0; sc1 = sn1;
  }

  // ---- epilogue ----
  float ls = lsumL;
  ls += __shfl_xor(ls, 16);
  ls += __shfl_xor(ls, 32);
  float inv = 1.0f / ls;
  int q = q0 + r0;
#pragma unroll
  for (int nf = 0; nf < 32; ++nf) {
    int d0 = nf * 16 + g * 4;
    float4 xr = *(const float4*)&x[((size_t)b * 2048 + q) * 512 + d0];
    s16x4 o;
    o[0] = f2h(accO[nf][0] * inv + xr.x);
    o[1] = f2h(accO[nf][1] * inv + xr.y);
    o[2] = f2h(accO[nf][2] * inv + xr.z);
    o[3] = f2h(accO[nf][3] * inv + xr.w);
    *(s16x4*)&y[((size_t)b * 2048 + q) * 512 + d0] = o;
  }
}

// ---------------- final GEMM: relu(y @ Wm + bm) -> f32 out ----------------

__global__ __launch_bounds__(256) void final_gemm_kernel(const short* __restrict__ A,
                                                         const short* __restrict__ Wt,
                                                         const float* __restrict__ bias,
                                                         float* __restrict__ out) {
  __shared__ __align__(16) short lds_a[128 * 40];
  __shared__ __align__(16) short lds_b[128 * 40];
  int tid = threadIdx.x, lane = tid & 63, w = tid >> 6;
  int wm = w >> 1, wn = w & 1;
  int bm = blockIdx.x * 128, bn = blockIdx.y * 128;

  f32x4 acc[4][4];
#pragma unroll
  for (int mi = 0; mi < 4; ++mi)
#pragma unroll
    for (int ni = 0; ni < 4; ++ni) acc[mi][ni] = (f32x4){0.f, 0.f, 0.f, 0.f};

  for (int k0 = 0; k0 < 512; k0 += 32) {
#pragma unroll
    for (int it = 0; it < 2; ++it) {
      int chunk = tid + it * 256;
      int row = chunk >> 2, c8 = (chunk & 3) * 8;
      *(s16x8*)&lds_a[row * 40 + c8] =
          *(const s16x8*)&A[(size_t)(bm + row) * 512 + k0 + c8];
      *(s16x8*)&lds_b[row * 40 + c8] =
          *(const s16x8*)&Wt[(bn + row) * 512 + k0 + c8];
    }
    __syncthreads();
    f16x8 af[4], bfr[4];
#pragma unroll
    for (int mi = 0; mi < 4; ++mi)
      af[mi] = *(const f16x8*)&lds_a[(wm * 64 + mi * 16 + (lane & 15)) * 40 +
                                     (lane >> 4) * 8];
#pragma unroll
    for (int ni = 0; ni < 4; ++ni)
      bfr[ni] = *(const f16x8*)&lds_b[(wn * 64 + ni * 16 + (lane & 15)) * 40 +
                                      (lane >> 4) * 8];
#pragma unroll
    for (int mi = 0; mi < 4; ++mi)
#pragma unroll
      for (int ni = 0; ni < 4; ++ni) acc[mi][ni] = MFMA(af[mi], bfr[ni], acc[mi][ni]);
    __syncthreads();
  }

#pragma unroll
  for (int mi = 0; mi < 4; ++mi)
#pragma unroll
    for (int ni = 0; ni < 4; ++ni) {
      int col = bn + wn * 64 + ni * 16 + (lane & 15);
      float bv = bias[col];
#pragma unroll
      for (int r = 0; r < 4; ++r) {
        int row = bm + wm * 64 + mi * 16 + (lane >> 4) * 4 + r;
        out[(size_t)row * 512 + col] = fmaxf(acc[mi][ni][r] + bv, 0.0f);
      }
    }
}

// ---------------- host launch ----------------

extern "C" void kernel_launch(void* const* d_in, const int* in_sizes, int n_in,
                              void* d_out, int out_size, void* d_ws, size_t ws_size,
                              hipStream_t stream) {
  const float* x  = (const float*)d_in[0];
  const float* Wh = (const float*)d_in[1];
  const float* bh = (const float*)d_in[2];
  const float* Wl = (const float*)d_in[3];
  const float* bl = (const float*)d_in[4];
  const float* Wg = (const float*)d_in[5];
  const float* bg = (const float*)d_in[6];
  const float* Wm = (const float*)d_in[7];
  const float* bm = (const float*)d_in[8];

  char* ws = (char*)d_ws;
  const size_t SZ = 16777216;
  short* xb  = (short*)(ws + 0 * SZ);
  short* h   = (short*)(ws + 1 * SZ);
  short* l   = (short*)(ws + 2 * SZ);
  short* gT  = (short*)(ws + 3 * SZ);
  short* y   = (short*)(ws + 4 * SZ);
  short* Wt  = (short*)(ws + 5 * SZ);

  conv_x_kernel<<<4096, 256, 0, stream>>>(x, xb);
  conv_w_kernel<<<4096, 256, 0, stream>>>(Wh, Wl, Wg, Wm, Wt);
  mlp3_kernel<<<dim3(128, 4, 3), 256, 0, stream>>>(xb, Wt, bh, bl, bg, h, l, gT);
  attn_kernel<<<256, 256, 0, stream>>>(l, h, gT, x, y);
  final_gemm_kernel<<<dim3(128, 4), 256, 0, stream>>>(y, Wt + 3 * 262144, bm,
                                                      (float*)d_out);
}

// Round 7
// 293.020 us; speedup vs baseline: 1.0115x; 1.0115x over previous
//
#include <hip/hip_runtime.h>

// B=8, N=2048, C=512. Flash attention + fp16 MFMA pipeline.
// attn r7: flash SPLIT-K across blocks (2 splits x 1024 keys) -> 2048 waves =
// 2 waves/SIMD. KVBLK=16, double-buffered K[16][512] (XOR-swizzled DMA) +
// G[512][16] (linear DMA), LDS 64KB -> 2 blocks/CU. PV via mfma 16x16x16:
// P-fragment == QK C-layout (no permlane). Per-split normalized O (fp16) +
// (m,l) sidecar; combine kernel merges + residual + y.
// ws: [0]=xb->OA [1]=h [2]=l [3]=gT [4]=OB->y [5]=Wt(2MB)+ml(256KB)

typedef __attribute__((ext_vector_type(4))) float f32x4;
typedef __attribute__((ext_vector_type(8))) short s16x8;      // fp16 bit-patterns
typedef __attribute__((ext_vector_type(4))) short s16x4;
typedef __attribute__((ext_vector_type(8))) _Float16 f16x8;   // MFMA operands
typedef __attribute__((ext_vector_type(4))) _Float16 f16x4;
typedef __attribute__((ext_vector_type(2))) unsigned u32x2;

typedef unsigned int u32;
typedef __attribute__((address_space(1))) const u32 gu32;
typedef __attribute__((address_space(3))) u32 lu32;

__device__ __forceinline__ void gload16(const short* g, short* l) {
  __builtin_amdgcn_global_load_lds((gu32*)g, (lu32*)l, 16, 0, 0);
}

__device__ __forceinline__ short f2h(float f) {
  _Float16 h = (_Float16)f;
  return __builtin_bit_cast(short, h);
}

__device__ __forceinline__ unsigned pk2h(float a, float b) {
  return __builtin_bit_cast(unsigned, __builtin_amdgcn_cvt_pkrtz(a, b));
}

#define MFMA(a, b, c) __builtin_amdgcn_mfma_f32_16x16x32_f16(a, b, c, 0, 0, 0)
#define MFMA16(a, b, c) __builtin_amdgcn_mfma_f32_16x16x16f16(a, b, c, 0, 0, 0)

// ---------------- conversion kernels ----------------

__global__ __launch_bounds__(256) void conv_x_kernel(const float* __restrict__ x,
                                                     short* __restrict__ xb) {
  int i = blockIdx.x * 256 + threadIdx.x;
  const float4* xv = (const float4*)x;
  float4 a = xv[2 * i], b = xv[2 * i + 1];
  s16x8 o;
  o[0] = f2h(a.x); o[1] = f2h(a.y); o[2] = f2h(a.z); o[3] = f2h(a.w);
  o[4] = f2h(b.x); o[5] = f2h(b.y); o[6] = f2h(b.z); o[7] = f2h(b.w);
  ((s16x8*)xb)[i] = o;
}

__global__ __launch_bounds__(256) void conv_w_kernel(const float* __restrict__ Wh,
                                                     const float* __restrict__ Wl,
                                                     const float* __restrict__ Wg,
                                                     const float* __restrict__ Wm,
                                                     short* __restrict__ Wt) {
  int idx = blockIdx.x * 256 + threadIdx.x;
  int k = idx & 511, n = (idx >> 9) & 511, w = idx >> 18;
  const float* W = (w == 0) ? Wh : (w == 1) ? Wl : (w == 2) ? Wg : Wm;
  Wt[idx] = f2h(W[k * 512 + n]);
}

// ---------------- fused 3-way MLP GEMM ----------------

__global__ __launch_bounds__(256) void mlp3_kernel(const short* __restrict__ A,
                                                   const short* __restrict__ Wt_all,
                                                   const float* __restrict__ bh,
                                                   const float* __restrict__ bl,
                                                   const float* __restrict__ bg,
                                                   short* __restrict__ h,
                                                   short* __restrict__ l,
                                                   short* __restrict__ gT) {
  int z = blockIdx.z;
  const short* Wt = Wt_all + z * 262144;
  const float* bias = (z == 0) ? bh : (z == 1) ? bl : bg;

  __shared__ __align__(16) short lds_a[128 * 40];
  __shared__ __align__(16) short lds_b[128 * 40];
  int tid = threadIdx.x, lane = tid & 63, w = tid >> 6;
  int wm = w >> 1, wn = w & 1;
  int bm = blockIdx.x * 128, bn = blockIdx.y * 128;

  f32x4 acc[4][4];
#pragma unroll
  for (int mi = 0; mi < 4; ++mi)
#pragma unroll
    for (int ni = 0; ni < 4; ++ni) acc[mi][ni] = (f32x4){0.f, 0.f, 0.f, 0.f};

  for (int k0 = 0; k0 < 512; k0 += 32) {
#pragma unroll
    for (int it = 0; it < 2; ++it) {
      int chunk = tid + it * 256;
      int row = chunk >> 2, c8 = (chunk & 3) * 8;
      *(s16x8*)&lds_a[row * 40 + c8] =
          *(const s16x8*)&A[(size_t)(bm + row) * 512 + k0 + c8];
      *(s16x8*)&lds_b[row * 40 + c8] =
          *(const s16x8*)&Wt[(bn + row) * 512 + k0 + c8];
    }
    __syncthreads();
    f16x8 af[4], bfr[4];
#pragma unroll
    for (int mi = 0; mi < 4; ++mi)
      af[mi] = *(const f16x8*)&lds_a[(wm * 64 + mi * 16 + (lane & 15)) * 40 +
                                     (lane >> 4) * 8];
#pragma unroll
    for (int ni = 0; ni < 4; ++ni)
      bfr[ni] = *(const f16x8*)&lds_b[(wn * 64 + ni * 16 + (lane & 15)) * 40 +
                                      (lane >> 4) * 8];
#pragma unroll
    for (int mi = 0; mi < 4; ++mi)
#pragma unroll
      for (int ni = 0; ni < 4; ++ni) acc[mi][ni] = MFMA(af[mi], bfr[ni], acc[mi][ni]);
    __syncthreads();
  }

#pragma unroll
  for (int mi = 0; mi < 4; ++mi)
#pragma unroll
    for (int ni = 0; ni < 4; ++ni) {
      int col = bn + wn * 64 + ni * 16 + (lane & 15);
      float bv = bias[col];
#pragma unroll
      for (int r = 0; r < 4; ++r) {
        int row = bm + wm * 64 + mi * 16 + (lane >> 4) * 4 + r;
        float v = fmaxf(acc[mi][ni][r] + bv, 0.0f);
        short o = f2h(v);
        if (z == 0) h[(size_t)row * 512 + col] = o;
        else if (z == 1) l[(size_t)row * 512 + col] = o;
        else {
          int bb = row >> 11, mm = row & 2047;
          gT[((size_t)bb * 512 + col) * 2048 + mm] = o;
        }
      }
    }
}

// ---------------- flash attention, split-K ----------------
// 512 blocks x 256 threads. Block: (batch, q-tile of 64, split sp of 1024 keys).
// 4 waves x 16 q. Per tile (16 keys): QK 16x16x32 (S^T, lane-local softmax),
// PV 16x16x16 (P-frag = C-layout, no cross-lane). 1 barrier/tile, dbuf K+G.

__global__ __launch_bounds__(256, 2) void attn_split_kernel(
    const short* __restrict__ lmat, const short* __restrict__ hmat,
    const short* __restrict__ gT,
    short* __restrict__ OA, short* __restrict__ OB,
    float2* __restrict__ mlA, float2* __restrict__ mlB) {
  __shared__ __align__(16) short kbuf[2][8192];  // [16 keys][512], XOR-swizzled
  __shared__ __align__(16) short gbuf[2][8192];  // [512 c][16 keys], linear
  int tid = threadIdx.x, lane = tid & 63, w = tid >> 6;
  int b = blockIdx.x & 7;           // XCD j <- batch j (round-robin dispatch)
  int idx = blockIdx.x >> 3;        // 0..63
  int qt = idx >> 1, sp = idx & 1;
  int q0 = qt * 64 + w * 16;
  int keybase = sp * 1024;
  const short* lb = lmat + (size_t)b * 2048 * 512;
  const short* hb = hmat + (size_t)b * 2048 * 512;
  const short* gb = gT + (size_t)b * 512 * 2048;
  short* Op = sp ? OB : OA;
  float2* ml = sp ? mlB : mlA;

  int r0 = lane & 15, g = lane >> 4;

  // Q fragments (B-operand: lane&15 = query col, k-chunk g*8): 64 VGPR
  f16x8 qf[16];
  {
    int q = q0 + r0;
#pragma unroll
    for (int ks = 0; ks < 16; ++ks)
      qf[ks] = *(const f16x8*)&lb[(size_t)q * 512 + ks * 32 + g * 8];
  }
  f32x4 accO[32];  // O^T: query r0, d = nf*16 + g*4 + r
#pragma unroll
  for (int i = 0; i < 32; ++i) accO[i] = (f32x4){0.f, 0.f, 0.f, 0.f};
  float mrun = -3e38f, lsumL = 0.f;

  auto stageK = [&](int buf, int t) {
    int key0 = keybase + t * 16;
    short* kd = &kbuf[buf][0];
#pragma unroll
    for (int j = 0; j < 4; ++j) {
      int wl = w * 4 + j;  // key row 0..15
      gload16(hb + (size_t)(key0 + wl) * 512 + (((lane * 16) ^ ((wl & 7) << 4)) >> 1),
              kd + wl * 512);
    }
  };
  auto stageG = [&](int buf, int t) {
    int key0 = keybase + t * 16;
    short* gd = &gbuf[buf][0];
#pragma unroll
    for (int j = 0; j < 4; ++j) {
      int wl = w * 4 + j;
      int row = wl * 32 + (lane >> 1);  // c row 0..511
      gload16(gb + (size_t)row * 2048 + key0 + (lane & 1) * 8, gd + wl * 512);
    }
  };
  auto QK = [&](int buf, f32x4& o) {
    const short* kb = &kbuf[buf][0];
#pragma unroll
    for (int ks = 0; ks < 16; ++ks) {
      f16x8 kf = *(const f16x8*)&kb[(r0 * 512 + ks * 32 + g * 8) ^ ((r0 & 7) << 3)];
      o = MFMA(kf, qf[ks], o);
    }
  };

  stageK(0, 0); stageG(0, 0); stageK(1, 1);
  __syncthreads();
  f32x4 sc = {0.f, 0.f, 0.f, 0.f};
  QK(0, sc);
  __syncthreads();

  for (int t = 0; t < 64; ++t) {
    if (t < 62) stageK(t & 1, t + 2);
    if (t < 63) stageG((t + 1) & 1, t + 1);

    f32x4 sn = {0.f, 0.f, 0.f, 0.f};
    if (t < 63) {
      __builtin_amdgcn_s_setprio(1);
      QK((t + 1) & 1, sn);
      __builtin_amdgcn_s_setprio(0);
    }

    // ---- softmax(t): 4 scores/lane (keys g*4+r), lane-local + 2 shuffles ----
    float m2 = fmaxf(fmaxf(sc[0], sc[1]), fmaxf(sc[2], sc[3]));
    m2 = fmaxf(m2, __shfl_xor(m2, 16));
    m2 = fmaxf(m2, __shfl_xor(m2, 32));
    bool ok = (m2 <= mrun + 8.0f);  // defer-max THR=8
    if (!__all((int)ok)) {
      float mnew = fmaxf(mrun, m2);
      float s = __expf(mrun - mnew);
      mrun = mnew;
      lsumL *= s;
#pragma unroll
      for (int nf = 0; nf < 32; ++nf) accO[nf] *= s;
    }
    float p0 = __expf(sc[0] - mrun), p1 = __expf(sc[1] - mrun);
    float p2 = __expf(sc[2] - mrun), p3 = __expf(sc[3] - mrun);
    lsumL += (p0 + p1) + (p2 + p3);

    // P-fragment: 16x16x16 B-operand k-slots (g*4+j) == QK C rows. No shuffles.
    u32x2 pw = {pk2h(p0, p1), pk2h(p2, p3)};
    f16x4 pfrag = __builtin_bit_cast(f16x4, pw);

    // ---- PV(t): O^T += G-frag x P-frag (k=16) ----
    const short* gp = &gbuf[t & 1][0];
    __builtin_amdgcn_s_setprio(1);
#pragma unroll
    for (int nf = 0; nf < 32; ++nf) {
      f16x4 gf = *(const f16x4*)&gp[(nf * 16 + r0) * 16 + g * 4];
      accO[nf] = MFMA16(gf, pfrag, accO[nf]);
    }
    __builtin_amdgcn_s_setprio(0);

    __syncthreads();
    sc = sn;
  }

  // ---- epilogue: store normalized O (fp16) + (m, l) sidecar ----
  float ls = lsumL;
  ls += __shfl_xor(ls, 16);
  ls += __shfl_xor(ls, 32);
  float inv = 1.0f / ls;
  int q = q0 + r0;
#pragma unroll
  for (int nf = 0; nf < 32; ++nf) {
    s16x4 o;
    o[0] = f2h(accO[nf][0] * inv);
    o[1] = f2h(accO[nf][1] * inv);
    o[2] = f2h(accO[nf][2] * inv);
    o[3] = f2h(accO[nf][3] * inv);
    *(s16x4*)&Op[((size_t)b * 2048 + q) * 512 + nf * 16 + g * 4] = o;
  }
  if (g == 0) ml[(size_t)b * 2048 + q] = make_float2(mrun, ls);
}

// ---------------- split-K combine + residual -> y (fp16) ----------------

__global__ __launch_bounds__(256) void combine_kernel(
    const short* __restrict__ OA, const short* __restrict__ OB,
    const float2* __restrict__ mlA, const float2* __restrict__ mlB,
    const float* __restrict__ x, short* __restrict__ y) {
  int i = blockIdx.x * 256 + threadIdx.x;  // 1M threads x 8 elems
  int base = i * 8, q = i >> 6;
  float2 a = mlA[q], c = mlB[q];
  float ms = fmaxf(a.x, c.x);
  float wA = __expf(a.x - ms) * a.y;
  float wB = __expf(c.x - ms) * c.y;
  float inv = 1.0f / (wA + wB);
  f16x8 oa = *(const f16x8*)&OA[base];
  f16x8 ob = *(const f16x8*)&OB[base];
  float4 x0 = *(const float4*)&x[base];
  float4 x1 = *(const float4*)&x[base + 4];
  s16x8 o;
  o[0] = f2h(((float)oa[0] * wA + (float)ob[0] * wB) * inv + x0.x);
  o[1] = f2h(((float)oa[1] * wA + (float)ob[1] * wB) * inv + x0.y);
  o[2] = f2h(((float)oa[2] * wA + (float)ob[2] * wB) * inv + x0.z);
  o[3] = f2h(((float)oa[3] * wA + (float)ob[3] * wB) * inv + x0.w);
  o[4] = f2h(((float)oa[4] * wA + (float)ob[4] * wB) * inv + x1.x);
  o[5] = f2h(((float)oa[5] * wA + (float)ob[5] * wB) * inv + x1.y);
  o[6] = f2h(((float)oa[6] * wA + (float)ob[6] * wB) * inv + x1.z);
  o[7] = f2h(((float)oa[7] * wA + (float)ob[7] * wB) * inv + x1.w);
  *(s16x8*)&y[base] = o;
}

// ---------------- final GEMM: relu(y @ Wm + bm) -> f32 out ----------------

__global__ __launch_bounds__(256) void final_gemm_kernel(const short* __restrict__ A,
                                                         const short* __restrict__ Wt,
                                                         const float* __restrict__ bias,
                                                         float* __restrict__ out) {
  __shared__ __align__(16) short lds_a[128 * 40];
  __shared__ __align__(16) short lds_b[128 * 40];
  int tid = threadIdx.x, lane = tid & 63, w = tid >> 6;
  int wm = w >> 1, wn = w & 1;
  int bm = blockIdx.x * 128, bn = blockIdx.y * 128;

  f32x4 acc[4][4];
#pragma unroll
  for (int mi = 0; mi < 4; ++mi)
#pragma unroll
    for (int ni = 0; ni < 4; ++ni) acc[mi][ni] = (f32x4){0.f, 0.f, 0.f, 0.f};

  for (int k0 = 0; k0 < 512; k0 += 32) {
#pragma unroll
    for (int it = 0; it < 2; ++it) {
      int chunk = tid + it * 256;
      int row = chunk >> 2, c8 = (chunk & 3) * 8;
      *(s16x8*)&lds_a[row * 40 + c8] =
          *(const s16x8*)&A[(size_t)(bm + row) * 512 + k0 + c8];
      *(s16x8*)&lds_b[row * 40 + c8] =
          *(const s16x8*)&Wt[(bn + row) * 512 + k0 + c8];
    }
    __syncthreads();
    f16x8 af[4], bfr[4];
#pragma unroll
    for (int mi = 0; mi < 4; ++mi)
      af[mi] = *(const f16x8*)&lds_a[(wm * 64 + mi * 16 + (lane & 15)) * 40 +
                                     (lane >> 4) * 8];
#pragma unroll
    for (int ni = 0; ni < 4; ++ni)
      bfr[ni] = *(const f16x8*)&lds_b[(wn * 64 + ni * 16 + (lane & 15)) * 40 +
                                      (lane >> 4) * 8];
#pragma unroll
    for (int mi = 0; mi < 4; ++mi)
#pragma unroll
      for (int ni = 0; ni < 4; ++ni) acc[mi][ni] = MFMA(af[mi], bfr[ni], acc[mi][ni]);
    __syncthreads();
  }

#pragma unroll
  for (int mi = 0; mi < 4; ++mi)
#pragma unroll
    for (int ni = 0; ni < 4; ++ni) {
      int col = bn + wn * 64 + ni * 16 + (lane & 15);
      float bv = bias[col];
#pragma unroll
      for (int r = 0; r < 4; ++r) {
        int row = bm + wm * 64 + mi * 16 + (lane >> 4) * 4 + r;
        out[(size_t)row * 512 + col] = fmaxf(acc[mi][ni][r] + bv, 0.0f);
      }
    }
}

// ---------------- host launch ----------------

extern "C" void kernel_launch(void* const* d_in, const int* in_sizes, int n_in,
                              void* d_out, int out_size, void* d_ws, size_t ws_size,
                              hipStream_t stream) {
  const float* x  = (const float*)d_in[0];
  const float* Wh = (const float*)d_in[1];
  const float* bh = (const float*)d_in[2];
  const float* Wl = (const float*)d_in[3];
  const float* bl = (const float*)d_in[4];
  const float* Wg = (const float*)d_in[5];
  const float* bg = (const float*)d_in[6];
  const float* Wm = (const float*)d_in[7];
  const float* bm = (const float*)d_in[8];

  char* ws = (char*)d_ws;
  const size_t SZ = 16777216;
  short*  xb  = (short*)(ws + 0 * SZ);   // conv_x out; reused as OA by attn
  short*  h   = (short*)(ws + 1 * SZ);
  short*  l   = (short*)(ws + 2 * SZ);
  short*  gT  = (short*)(ws + 3 * SZ);
  short*  yOB = (short*)(ws + 4 * SZ);   // OB during attn, then y (in-place)
  short*  Wt  = (short*)(ws + 5 * SZ);   // 2 MB
  float2* mlA = (float2*)(ws + 5 * SZ + 2097152);            // 128 KB
  float2* mlB = (float2*)(ws + 5 * SZ + 2097152 + 131072);   // 128 KB

  conv_x_kernel<<<4096, 256, 0, stream>>>(x, xb);
  conv_w_kernel<<<4096, 256, 0, stream>>>(Wh, Wl, Wg, Wm, Wt);
  mlp3_kernel<<<dim3(128, 4, 3), 256, 0, stream>>>(xb, Wt, bh, bl, bg, h, l, gT);
  attn_split_kernel<<<512, 256, 0, stream>>>(l, h, gT, xb, yOB, mlA, mlB);
  combine_kernel<<<4096, 256, 0, stream>>>(xb, yOB, mlA, mlB, x, yOB);
  final_gemm_kernel<<<dim3(128, 4), 256, 0, stream>>>(yOB, Wt + 3 * 262144, bm,
                                                      (float*)d_out);
}